// Round 3
// baseline (39161.267 us; speedup 1.0000x reference)
//
#include <hip/hip_runtime.h>
#include <math.h>

#define NA 159375
static constexpr size_t OFF_LOCS   = 0;        // 2*NA*4 = 1,275,000
static constexpr size_t OFF_SCORES = 1275000;  // 2*NA*2 =   637,500
static constexpr size_t OFF_ROIS   = 1912500;  // 600*4  =     2,400
static constexpr size_t OFF_RI     = 1914900;  // 600
static constexpr size_t OFF_ANCH   = 1915500;  // NA*4   =   637,500
#define MONO_NEGINF 0x007FFFFFu

// ---------------- weight transpose: wT[(ic*9+tap)*512 + oc] = w[oc][ic][tap]
__global__ void k_wT(const float* __restrict__ w, float* __restrict__ wT) {
  int idx = blockIdx.x * 256 + threadIdx.x;
  if (idx >= 512 * 512 * 9) return;
  int oc = idx & 511;
  int row = idx >> 9;               // ic*9 + tap
  int ic = row / 9, tap = row - ic * 9;
  wT[idx] = w[((size_t)oc * 512 + ic) * 9 + tap];
}

// async global->LDS, 16B per lane. Dest = wave-uniform base + lane*16.
__device__ __forceinline__ void gload16(const float* g, float* l) {
  __builtin_amdgcn_global_load_lds(
      (const __attribute__((address_space(1))) unsigned int*)(g),
      (__attribute__((address_space(3))) unsigned int*)(l), 16, 0, 0);
}

// ---------------- fused conv3x3(512->512)+relu + 1x1 loc(12)/score(6) heads
// One dispatch: all 4 levels x 2 images. Block 512 thr, tile 8x8 px x 512 oc.
// R3: double-buffered LDS (weights via global_load_lds DMA, input via
// reg-stage early-load/late-write), ONE barrier per ic-chunk. R2 had 2
// barriers/iter + no prefetch -> 30% of cycles nothing could issue
// (VALUBusy 68%, occ 23.5%).
__global__
__attribute__((amdgpu_flat_work_group_size(512, 512), amdgpu_waves_per_eu(2, 4)))
void k_conv(
    const float* __restrict__ fm0, const float* __restrict__ fm1,
    const float* __restrict__ fm2, const float* __restrict__ fm3,
    const float* __restrict__ wT,
    const float* __restrict__ cb, const float* __restrict__ locw,
    const float* __restrict__ locb, const float* __restrict__ scow,
    const float* __restrict__ scob, float* __restrict__ out) {
  const int tb_ = blockIdx.x;
  const int b = blockIdx.y;
  int H, locbase, nt, tile;
  const float* fmb;
  if (tb_ < 625)      { H = 200; locbase = 0;     nt = 25; tile = tb_;       fmb = fm0; }
  else if (tb_ < 794) { H = 100; locbase = 40000; nt = 13; tile = tb_ - 625; fmb = fm1; }
  else if (tb_ < 843) { H = 50;  locbase = 50000; nt = 7;  tile = tb_ - 794; fmb = fm2; }
  else                { H = 25;  locbase = 52500; nt = 4;  tile = tb_ - 843; fmb = fm3; }
  const int W = H;
  const int ty_t = tile / nt, tx_t = tile - ty_t * nt;
  const int x0 = tx_t * 8, y0 = ty_t * 8;
  fmb += (size_t)b * 512 * H * W;

  const int tid = threadIdx.x;
  const int wv = tid >> 6;            // wave index 0..7 (uniform per wave)
  const int pxg = tid & 15, ocg = tid >> 4;
  const int ty = pxg >> 1, tx0 = (pxg & 1) * 4;

  __shared__ alignas(16) union LDS {
    struct { float w[2][9216]; float in[2][2][10][12]; } m;  // 75648 B
    struct { float h[64 * 132]; float w1[18 * 128]; } e;     // 43008 B
  } lds;

  float acc[4][16];
#pragma unroll
  for (int q = 0; q < 4; q++)
#pragma unroll
    for (int i = 0; i < 16; i++) acc[q][i] = 0.f;

  // input-halo staging geometry (constant per thread)
  const bool stg = (tid < 200);
  int sic = 0, srr = 0, scc = 0; bool sok = false; size_t soff = 0;
  if (stg) {
    sic = tid / 100; int rem = tid % 100; srr = rem / 10; scc = rem % 10;
    int yy = y0 - 1 + srr, xx = x0 - 1 + scc;
    sok = (yy >= 0 && yy < H && xx >= 0 && xx < W);
    if (sok) soff = ((size_t)sic * H + yy) * W + xx;
  }

  // stage chunk t (ic0=2t) into buffer nb; returns input value (reg)
  auto stage = [&](int t, int nb) -> float {
    float iv = 0.f;
    if (stg && sok) iv = fmb[(size_t)2 * t * H * W + soff];   // issued early
    const float* wsrc = wT + (size_t)t * 9216;
    float* wb = lds.m.w[nb];
#pragma unroll
    for (int k = 0; k < 4; k++)
      gload16(wsrc + k * 2048 + tid * 4, wb + k * 2048 + wv * 256);
    if (wv < 4)
      gload16(wsrc + 8192 + tid * 4, wb + 8192 + wv * 256);
    return iv;
  };

  auto compute = [&](int cb2) {
#pragma unroll
    for (int ic = 0; ic < 2; ic++) {
#pragma unroll
      for (int ky = 0; ky < 3; ky++) {
        const float* rowp = &lds.m.in[cb2][ic][ty + ky][tx0];
        float4 rlo = *reinterpret_cast<const float4*>(rowp);
        float2 rhi = *reinterpret_cast<const float2*>(rowp + 4);
        float r[6] = {rlo.x, rlo.y, rlo.z, rlo.w, rhi.x, rhi.y};
#pragma unroll
        for (int kx = 0; kx < 3; kx++) {
          const float4* wp = reinterpret_cast<const float4*>(
              &lds.m.w[cb2][(ic * 9 + ky * 3 + kx) * 512 + ocg * 16]);
#pragma unroll
          for (int v4 = 0; v4 < 4; v4++) {
            float4 wvv = wp[v4];
#pragma unroll
            for (int q = 0; q < 4; q++) {
              float ivv = r[q + kx];
              acc[q][v4 * 4 + 0] = fmaf(ivv, wvv.x, acc[q][v4 * 4 + 0]);
              acc[q][v4 * 4 + 1] = fmaf(ivv, wvv.y, acc[q][v4 * 4 + 1]);
              acc[q][v4 * 4 + 2] = fmaf(ivv, wvv.z, acc[q][v4 * 4 + 2]);
              acc[q][v4 * 4 + 3] = fmaf(ivv, wvv.w, acc[q][v4 * 4 + 3]);
            }
          }
        }
      }
    }
  };

  // prologue: stage chunk 0 -> buf 0
  {
    float iv = stage(0, 0);
    if (stg) lds.m.in[0][sic][srr][scc] = iv;
  }
  __syncthreads();

  int cur = 0;
#pragma unroll 1
  for (int t = 0; t < 255; ++t) {
    float iv = stage(t + 1, cur ^ 1);   // async prefetch (DMA + reg)
    compute(cur);                        // hides the prefetch latency
    if (stg) lds.m.in[cur ^ 1][sic][srr][scc] = iv;  // late ds_write
    __syncthreads();                     // drains vmcnt+lgkmcnt, one barrier
    cur ^= 1;
  }
  compute(cur);                          // last chunk

  // bias + relu
#pragma unroll
  for (int i = 0; i < 16; i++) {
    float bb = cb[ocg * 16 + i];
#pragma unroll
    for (int q = 0; q < 4; q++) acc[q][i] = fmaxf(__fadd_rn(acc[q][i], bb), 0.f);
  }

  // fused 1x1 heads: 18 channels (12 loc + 6 score), reduce 512 oc in 4 chunks of 128
  float part[3] = {0.f, 0.f, 0.f};
#pragma unroll 1
  for (int c = 0; c < 4; c++) {
    __syncthreads();
    for (int idx = tid; idx < 18 * 128; idx += 512) {
      int ch = idx >> 7, j = idx & 127;
      lds.e.w1[idx] = (ch < 12) ? locw[ch * 512 + c * 128 + j]
                                : scow[(ch - 12) * 512 + c * 128 + j];
    }
    if ((ocg >> 3) == c) {
      int ocl = (ocg & 7) * 16;
#pragma unroll
      for (int q = 0; q < 4; q++)
#pragma unroll
        for (int i = 0; i < 16; i++)
          lds.e.h[(pxg * 4 + q) * 132 + ocl + i] = acc[q][i];
    }
    __syncthreads();
#pragma unroll
    for (int pp = 0; pp < 3; pp++) {
      int pair = tid + pp * 512;
      if (pair < 1152) {
        int px = pair & 63, ch = pair >> 6;
        const float4* hp = reinterpret_cast<const float4*>(&lds.e.h[px * 132]);
        const float4* wp = reinterpret_cast<const float4*>(&lds.e.w1[ch * 128]);
        float s = part[pp];
#pragma unroll
        for (int j = 0; j < 32; j++) {
          float4 h4 = hp[j], w4 = wp[j];
          s = fmaf(h4.x, w4.x, fmaf(h4.y, w4.y, fmaf(h4.z, w4.z, fmaf(h4.w, w4.w, s))));
        }
        part[pp] = s;
      }
    }
  }
  // write NHWC-flattened loc/score outputs
#pragma unroll
  for (int pp = 0; pp < 3; pp++) {
    int pair = tid + pp * 512;
    if (pair < 1152) {
      int px = pair & 63, ch = pair >> 6;
      int y = y0 + (px >> 3), x = x0 + (px & 7);
      if (y < H && x < W) {
        int k = locbase + y * W + x;
        if (ch < 12) {
          int a = ch >> 2, d = ch & 3;
          int n = 3 * k + a;
          out[OFF_LOCS + ((size_t)b * NA + n) * 4 + d] = __fadd_rn(part[pp], locb[ch]);
        } else {
          int s = ch - 12, a = s >> 1, si = s & 1;
          int n = 3 * k + a;
          out[OFF_SCORES + ((size_t)b * NA + n) * 2 + si] = __fadd_rn(part[pp], scob[s]);
        }
      }
    }
  }
}

// ---------------- anchors (double math to mirror numpy exactly)
__global__ void k_anchors(float* __restrict__ out) {
  int n = blockIdx.x * 256 + threadIdx.x;
  if (n >= NA) return;
  int a = n % 3, k = n / 3;
  int base, Wl, stride, scale;
  if (k < 40000)      { base = 0;     Wl = 200; stride = 4;  scale = 4; }
  else if (k < 50000) { base = 40000; Wl = 100; stride = 8;  scale = 8; }
  else if (k < 52500) { base = 50000; Wl = 50;  stride = 16; scale = 16; }
  else                { base = 52500; Wl = 25;  stride = 32; scale = 32; }
  int kk = k - base;
  int ky = kk / Wl, kx = kk - ky * Wl;
  double r = (a == 0) ? 0.5 : ((a == 1) ? 1.0 : 2.0);
  double sc = (double)scale;
  double h = (16.0 * sc) * sqrt(r);
  double w = (16.0 * sc) * sqrt(1.0 / r);
  float ab0 = (float)(8.0 - h / 2.0), ab1 = (float)(8.0 - w / 2.0);
  float ab2 = (float)(8.0 + h / 2.0), ab3 = (float)(8.0 + w / 2.0);
  double sy = (double)(ky * stride), sx = (double)(kx * stride);
  out[OFF_ANCH + (size_t)n * 4 + 0] = (float)((double)ab0 + sy);
  out[OFF_ANCH + (size_t)n * 4 + 1] = (float)((double)ab1 + sx);
  out[OFF_ANCH + (size_t)n * 4 + 2] = (float)((double)ab2 + sy);
  out[OFF_ANCH + (size_t)n * 4 + 3] = (float)((double)ab3 + sx);
}

// ---------------- zero hists + counters
__global__ void k_zero(unsigned* hhi, unsigned* hlo, unsigned* misc) {
  int i = blockIdx.x * 256 + threadIdx.x;
  if (i < 2 * 65536) { hhi[i] = 0u; hlo[i] = 0u; }
  if (i < 64) misc[i] = 0u;
}

// ---------------- decode boxes, fg softmax, validity mask, monotone key
__global__ void k_decode(const float* __restrict__ out, float* __restrict__ boxes,
                         unsigned* __restrict__ keys, const int* __restrict__ ihp,
                         const int* __restrict__ iwp) {
  int n = blockIdx.x * 256 + threadIdx.x;
  int b = blockIdx.y;
  if (n >= NA) return;
  const float* an = out + OFF_ANCH + (size_t)n * 4;
  float a0 = an[0], a1 = an[1], a2 = an[2], a3 = an[3];
  const float* lc = out + OFF_LOCS + ((size_t)b * NA + n) * 4;
  float l0 = lc[0], l1 = lc[1], l2 = lc[2], l3 = lc[3];
  const float* sp = out + OFF_SCORES + ((size_t)b * NA + n) * 2;
  float s0 = sp[0], s1 = sp[1];
  float m = fmaxf(s0, s1);
  float e0 = expf(__fsub_rn(s0, m)), e1 = expf(__fsub_rn(s1, m));
  float fg = __fdiv_rn(e1, __fadd_rn(e0, e1));
  float ah = __fsub_rn(a2, a0), aw = __fsub_rn(a3, a1);
  float acy = __fadd_rn(a0, __fmul_rn(0.5f, ah));
  float acx = __fadd_rn(a1, __fmul_rn(0.5f, aw));
  float cy = __fadd_rn(__fmul_rn(l0, ah), acy);
  float cx = __fadd_rn(__fmul_rn(l1, aw), acx);
  float hh = __fmul_rn(expf(l2), ah), ww = __fmul_rn(expf(l3), aw);
  float y1 = __fsub_rn(cy, __fmul_rn(0.5f, hh));
  float x1 = __fsub_rn(cx, __fmul_rn(0.5f, ww));
  float y2 = __fadd_rn(cy, __fmul_rn(0.5f, hh));
  float x2 = __fadd_rn(cx, __fmul_rn(0.5f, ww));
  float fh = (float)ihp[0], fw = (float)iwp[0];
  y1 = fminf(fmaxf(y1, 0.f), fh); x1 = fminf(fmaxf(x1, 0.f), fw);
  y2 = fminf(fmaxf(y2, 0.f), fh); x2 = fminf(fmaxf(x2, 0.f), fw);
  float hs = __fsub_rn(y2, y1), wsz = __fsub_rn(x2, x1);
  bool valid = (hs >= 16.f) && (wsz >= 16.f);
  float scv = valid ? fg : -INFINITY;
  size_t bi = (size_t)b * NA + n;
  boxes[bi * 4 + 0] = y1; boxes[bi * 4 + 1] = x1;
  boxes[bi * 4 + 2] = y2; boxes[bi * 4 + 3] = x2;
  unsigned u = __float_as_uint(scv);
  keys[bi] = (u & 0x80000000u) ? ~u : (u | 0x80000000u);
}

__global__ void k_hist_hi(const unsigned* __restrict__ keys, unsigned* __restrict__ hhi) {
  int n = blockIdx.x * 256 + threadIdx.x;
  int b = blockIdx.y;
  if (n >= NA) return;
  unsigned k = keys[(size_t)b * NA + n];
  atomicAdd(&hhi[b * 65536 + (k >> 16)], 1u);
}

__global__ void k_hist_lo(const unsigned* __restrict__ keys, const unsigned* __restrict__ misc,
                          unsigned* __restrict__ hlo) {
  int n = blockIdx.x * 256 + threadIdx.x;
  int b = blockIdx.y;
  if (n >= NA) return;
  unsigned bhi = misc[b * 32 + 2];
  unsigned k = keys[(size_t)b * NA + n];
  if ((k >> 16) == bhi) atomicAdd(&hlo[b * 65536 + (k & 0xFFFFu)], 1u);
}

// find the target-th largest bucket; mode0: target=2000 over hi16, mode1: rank over lo16
__global__ __launch_bounds__(1024) void k_scan(const unsigned* __restrict__ hist,
                                               unsigned* __restrict__ misc, int mode) {
  int b = blockIdx.x;
  const unsigned* h = hist + (size_t)b * 65536;
  unsigned* mc = misc + b * 32;
  __shared__ unsigned part[1024];
  int t = threadIdx.x;
  unsigned target = (mode == 0) ? 2000u : mc[3];
  unsigned s = 0;
  for (int i = 0; i < 64; i++) s += h[t * 64 + i];
  part[t] = s;
  __syncthreads();
  if (t == 0) {
    unsigned cum = 0; int seg = 0;
    for (int u = 1023; u >= 0; --u) {
      if (cum + part[u] >= target) { seg = u; break; }
      cum += part[u];
    }
    unsigned c2 = cum; int bin = seg * 64;
    for (int v = seg * 64 + 63; v >= seg * 64; --v) {
      if (c2 + h[v] >= target) { bin = v; break; }
      c2 += h[v];
    }
    if (mode == 0) { mc[2] = (unsigned)bin; mc[3] = target - c2; }
    else {
      unsigned T = (mc[2] << 16) | (unsigned)bin;
      unsigned cnt_gt = (2000u - mc[3]) + c2;
      mc[4] = T; mc[5] = cnt_gt; mc[6] = 2000u - cnt_gt;
    }
  }
}

__global__ void k_collect(const unsigned* __restrict__ keys, unsigned* __restrict__ misc,
                          unsigned long long* __restrict__ sel, unsigned* __restrict__ ties) {
  int n = blockIdx.x * 256 + threadIdx.x;
  int b = blockIdx.y;
  if (n >= NA) return;
  unsigned T = misc[b * 32 + 4];
  unsigned k = keys[(size_t)b * NA + n];
  if (k > T) {
    unsigned p = atomicAdd(&misc[b * 32 + 0], 1u);
    if (p < 2048) sel[(size_t)b * 2048 + p] = ((unsigned long long)k << 32) | (unsigned)(~n);
  } else if (k == T) {
    unsigned p = atomicAdd(&misc[b * 32 + 1], 1u);
    if (p < 8192) ties[(size_t)b * 8192 + p] = (unsigned)n;
  }
}

// build top-2000 sorted by (score desc, idx asc); gather boxes; init keep bits
__global__ __launch_bounds__(1024) void k_final(
    const unsigned long long* __restrict__ sel, const unsigned* __restrict__ ties,
    const unsigned* __restrict__ misc, const float* __restrict__ boxes,
    float* __restrict__ tb, unsigned long long* __restrict__ keepw) {
  int b = blockIdx.x, t = threadIdx.x;
  __shared__ unsigned tie_s[8192];
  __shared__ unsigned long long arr[2048];
  __shared__ unsigned long long kw[32];
  unsigned cnt_gt = misc[b * 32 + 5];
  unsigned cnt_eq = misc[b * 32 + 1]; if (cnt_eq > 8192u) cnt_eq = 8192u;
  unsigned T = misc[b * 32 + 4];
  unsigned msort = 64;
  while (msort < cnt_eq) msort <<= 1;
  for (int i = t; i < 8192; i += 1024)
    tie_s[i] = (i < (int)cnt_eq) ? ties[(size_t)b * 8192 + i] : 0xFFFFFFFFu;
  __syncthreads();
  for (unsigned kk = 2; kk <= msort; kk <<= 1)
    for (unsigned j = kk >> 1; j > 0; j >>= 1) {
      for (int i = t; i < (int)msort; i += 1024) {
        int l = i ^ (int)j;
        if (l > i) {
          unsigned a = tie_s[i], c = tie_s[l];
          bool up = ((i & kk) == 0);               // ascending
          if ((a > c) == up) { tie_s[i] = c; tie_s[l] = a; }
        }
      }
      __syncthreads();
    }
  for (int i = t; i < 2048; i += 1024) {
    unsigned long long v = 0ull;
    if (i < (int)cnt_gt) v = sel[(size_t)b * 2048 + i];
    else if (i < 2000) {
      unsigned n = tie_s[i - cnt_gt];
      v = ((unsigned long long)T << 32) | (unsigned)(~n);
    }
    arr[i] = v;
  }
  __syncthreads();
  for (unsigned kk = 2; kk <= 2048; kk <<= 1)
    for (unsigned j = kk >> 1; j > 0; j >>= 1) {
      for (int i = t; i < 2048; i += 1024) {
        int l = i ^ (int)j;
        if (l > i) {
          unsigned long long a = arr[i], c = arr[l];
          bool dir = ((i & kk) != 0);              // descending overall
          if ((a > c) == dir) { arr[i] = c; arr[l] = a; }
        }
      }
      __syncthreads();
    }
  if (t < 32) kw[t] = 0ull;
  __syncthreads();
  for (int j = t; j < 2000; j += 1024) {
    unsigned long long v = arr[j];
    unsigned n = ~(unsigned)(v & 0xFFFFFFFFull);
    unsigned key = (unsigned)(v >> 32);
    const float* bp = boxes + ((size_t)b * NA + n) * 4;
    float* tp = tb + ((size_t)b * 2000 + j) * 4;
    tp[0] = bp[0]; tp[1] = bp[1]; tp[2] = bp[2]; tp[3] = bp[3];
    if (key > MONO_NEGINF) atomicOr(&kw[j >> 6], 1ull << (j & 63));
  }
  __syncthreads();
  if (t < 32) keepw[b * 32 + t] = kw[t];
}

// ---------------- IoU suppression bitmask (j > i, iou > 0.7)
__device__ __forceinline__ int swz(int i) { return i + (i >> 8); }
__global__ __launch_bounds__(256) void k_iou(const float* __restrict__ tb,
                                             unsigned long long* __restrict__ mask) {
  int b = blockIdx.y;
  __shared__ float bx[8032];
  const float* tbb = tb + (size_t)b * 2000 * 4;
  for (int i = threadIdx.x; i < 8000; i += 256) bx[swz(i)] = tbb[i];
  __syncthreads();
  int il = threadIdx.x >> 5, w = threadIdx.x & 31;
  int i = blockIdx.x * 8 + il;
  int ib = i * 4, ip = ib + (ib >> 8);
  float y1 = bx[ip], x1 = bx[ip + 1], y2 = bx[ip + 2], x2 = bx[ip + 3];
  float ai = __fmul_rn(__fsub_rn(y2, y1), __fsub_rn(x2, x1));
  unsigned long long m = 0ull;
  int j0 = w * 64;
  for (int l = 0; l < 64; l++) {
    int j = j0 + l;
    if (j < 2000 && j > i) {
      int jb = j * 4, jp = jb + (jb >> 8);
      float yy1 = bx[jp], xx1 = bx[jp + 1], yy2 = bx[jp + 2], xx2 = bx[jp + 3];
      float aj = __fmul_rn(__fsub_rn(yy2, yy1), __fsub_rn(xx2, xx1));
      float iy = fmaxf(0.f, __fsub_rn(fminf(y2, yy2), fmaxf(y1, yy1)));
      float ix = fmaxf(0.f, __fsub_rn(fminf(x2, xx2), fmaxf(x1, xx1)));
      float inter = __fmul_rn(iy, ix);
      float den = __fadd_rn(__fsub_rn(__fadd_rn(ai, aj), inter), 1e-10f);
      if (__fdiv_rn(inter, den) > 0.7f) m |= (1ull << l);
    }
  }
  mask[((size_t)b * 2000 + i) * 32 + w] = m;
}

// ---------------- sequential greedy NMS (1 wave per image)
__device__ __forceinline__ unsigned long long shfl64(unsigned long long v, int src) {
  int lo = __shfl((int)(v & 0xFFFFFFFFull), src, 64);
  int hi = __shfl((int)(v >> 32), src, 64);
  return ((unsigned long long)(unsigned)hi << 32) | (unsigned)lo;
}
__global__ __launch_bounds__(64) void k_nms(const unsigned long long* __restrict__ mask,
                                            unsigned long long* __restrict__ keepw) {
  int b = blockIdx.x, lane = threadIdx.x;
  __shared__ unsigned long long rows[64][33];
  unsigned long long k = (lane < 32) ? keepw[b * 32 + lane] : 0ull;
  const unsigned long long* mb = mask + (size_t)b * 2000 * 32;
  for (int c = 0; c < 32; c++) {
    __syncthreads();
    for (int it = 0; it < 32; it++) {
      int idx = it * 64 + lane;
      int r = idx >> 5, w = idx & 31;
      int gi = c * 64 + r;
      rows[r][w] = (gi < 2000) ? mb[(size_t)gi * 32 + w] : 0ull;
    }
    __syncthreads();
    for (int il = 0; il < 64; il++) {
      int i = c * 64 + il;
      if (i >= 2000) break;
      unsigned long long kv = shfl64(k, i >> 6);
      if ((kv >> (i & 63)) & 1ull) {
        if (lane < 32) k &= ~rows[il][lane];
      }
    }
  }
  if (lane < 32) keepw[b * 32 + lane] = k;
}

// ---------------- compact kept boxes -> rois (+zero pad) + roi_indices
__global__ __launch_bounds__(1024) void k_rois(const unsigned long long* __restrict__ keepw,
                                               const float* __restrict__ tb,
                                               float* __restrict__ out) {
  int b = blockIdx.x, t = threadIdx.x;
  __shared__ unsigned long long kws[32];
  __shared__ unsigned pre[33];
  if (t < 32) kws[t] = keepw[b * 32 + t];
  __syncthreads();
  if (t == 0) {
    unsigned c = 0;
    for (int w = 0; w < 32; w++) { pre[w] = c; c += __popcll(kws[w]); }
    pre[32] = c;
  }
  __syncthreads();
  unsigned total = pre[32];
  for (int j = t; j < 2000; j += 1024) {
    unsigned long long kv = kws[j >> 6];
    if ((kv >> (j & 63)) & 1ull) {
      unsigned rank = pre[j >> 6] + (unsigned)__popcll(kv & ((1ull << (j & 63)) - 1ull));
      if (rank < 300) {
        const float* tp = tb + ((size_t)b * 2000 + j) * 4;
        float* op = out + OFF_ROIS + ((size_t)b * 300 + rank) * 4;
        op[0] = tp[0]; op[1] = tp[1]; op[2] = tp[2]; op[3] = tp[3];
      }
    }
  }
  for (int r = t; r < 300; r += 1024) {
    if ((unsigned)r >= total) {
      float* op = out + OFF_ROIS + ((size_t)b * 300 + r) * 4;
      op[0] = 0.f; op[1] = 0.f; op[2] = 0.f; op[3] = 0.f;
    }
    out[OFF_RI + b * 300 + r] = (float)b;
  }
}

extern "C" void kernel_launch(void* const* d_in, const int* in_sizes, int n_in,
                              void* d_out, int out_size, void* d_ws, size_t ws_size,
                              hipStream_t stream) {
  const float* fm0 = (const float*)d_in[0];
  const float* fm1 = (const float*)d_in[1];
  const float* fm2 = (const float*)d_in[2];
  const float* fm3 = (const float*)d_in[3];
  const float* cw  = (const float*)d_in[4];
  const float* cb  = (const float*)d_in[5];
  const float* scw = (const float*)d_in[6];
  const float* scb = (const float*)d_in[7];
  const float* lw  = (const float*)d_in[8];
  const float* lb  = (const float*)d_in[9];
  const int* ih = (const int*)d_in[10];
  const int* iw = (const int*)d_in[11];
  float* out = (float*)d_out;
  char* wsb = (char*)d_ws;

  auto al = [](size_t x) { return (x + 511) & ~(size_t)511; };
  size_t off = 0;
  float* wT = (float*)(wsb + off);                 off = al(off + (size_t)512 * 512 * 9 * 4);
  float* boxes = (float*)(wsb + off);              off = al(off + (size_t)2 * NA * 4 * 4);
  unsigned* keys = (unsigned*)(wsb + off);         off = al(off + (size_t)2 * NA * 4);
  unsigned* hhi = (unsigned*)(wsb + off);          off = al(off + (size_t)2 * 65536 * 4);
  unsigned* hlo = (unsigned*)(wsb + off);          off = al(off + (size_t)2 * 65536 * 4);
  unsigned* misc = (unsigned*)(wsb + off);         off = al(off + 64 * 4);
  unsigned long long* sel = (unsigned long long*)(wsb + off);  off = al(off + (size_t)2 * 2048 * 8);
  unsigned* ties = (unsigned*)(wsb + off);         off = al(off + (size_t)2 * 8192 * 4);
  float* tb = (float*)(wsb + off);                 off = al(off + (size_t)2 * 2000 * 4 * 4);
  unsigned long long* mask = (unsigned long long*)(wsb + off); off = al(off + (size_t)2 * 2000 * 32 * 8);
  unsigned long long* keep = (unsigned long long*)(wsb + off); off = al(off + (size_t)2 * 32 * 8);
  (void)ws_size; (void)in_sizes; (void)n_in; (void)out_size;

  k_wT<<<dim3((512 * 512 * 9 + 255) / 256), dim3(256), 0, stream>>>(cw, wT);

  // all 4 levels x 2 images in one dispatch: 625+169+49+16 = 859 tiles
  k_conv<<<dim3(859, 2), dim3(512), 0, stream>>>(fm0, fm1, fm2, fm3, wT, cb,
                                                 lw, lb, scw, scb, out);
  k_anchors<<<dim3(623), dim3(256), 0, stream>>>(out);
  k_zero<<<dim3(512), dim3(256), 0, stream>>>(hhi, hlo, misc);
  k_decode<<<dim3(623, 2), dim3(256), 0, stream>>>(out, boxes, keys, ih, iw);
  k_hist_hi<<<dim3(623, 2), dim3(256), 0, stream>>>(keys, hhi);
  k_scan<<<dim3(2), dim3(1024), 0, stream>>>(hhi, misc, 0);
  k_hist_lo<<<dim3(623, 2), dim3(256), 0, stream>>>(keys, misc, hlo);
  k_scan<<<dim3(2), dim3(1024), 0, stream>>>(hlo, misc, 1);
  k_collect<<<dim3(623, 2), dim3(256), 0, stream>>>(keys, misc, sel, ties);
  k_final<<<dim3(2), dim3(1024), 0, stream>>>(sel, ties, misc, boxes, tb, keep);
  k_iou<<<dim3(250, 2), dim3(256), 0, stream>>>(tb, mask);
  k_nms<<<dim3(2), dim3(64), 0, stream>>>(mask, keep);
  k_rois<<<dim3(2), dim3(1024), 0, stream>>>(keep, tb, out);
}

// Round 4
// 8111.618 us; speedup vs baseline: 4.8278x; 4.8278x over previous
//
#include <hip/hip_runtime.h>
#include <math.h>

#define NA 159375
static constexpr size_t OFF_LOCS   = 0;        // 2*NA*4 = 1,275,000
static constexpr size_t OFF_SCORES = 1275000;  // 2*NA*2 =   637,500
static constexpr size_t OFF_ROIS   = 1912500;  // 600*4  =     2,400
static constexpr size_t OFF_RI     = 1914900;  // 600
static constexpr size_t OFF_ANCH   = 1915500;  // NA*4   =   637,500
#define MONO_NEGINF 0x007FFFFFu

// ---------------- weight transpose: wT[(ic*9+tap)*512 + oc] = w[oc][ic][tap]
__global__ void k_wT(const float* __restrict__ w, float* __restrict__ wT) {
  int idx = blockIdx.x * 256 + threadIdx.x;
  if (idx >= 512 * 512 * 9) return;
  int oc = idx & 511;
  int row = idx >> 9;               // ic*9 + tap
  int ic = row / 9, tap = row - ic * 9;
  wT[idx] = w[((size_t)oc * 512 + ic) * 9 + tap];
}

// ---------------- fused conv3x3(512->512)+relu + 1x1 loc(12)/score(6) heads
// R4: tile = 16 rows x 8 cols x 512 oc per block; thread = 8 px x 16 oc
// (acc[8][16] = 128 VGPR). Weight LDS bytes/FMA halved vs R2 (0.5 B/FMA)
// -> FMA-issue bound, LDS ~60%. Single-buffer LDS, 2 barriers/chunk,
// plain reg-staged loads. R3 lesson: NO in-loop async prefetch next to a
// live 128-reg accumulator (RA spilled acc every iter -> 122 GB scratch).
__global__
__attribute__((amdgpu_flat_work_group_size(512, 512), amdgpu_waves_per_eu(2, 4)))
void k_conv(
    const float* __restrict__ fm0, const float* __restrict__ fm1,
    const float* __restrict__ fm2, const float* __restrict__ fm3,
    const float* __restrict__ wT,
    const float* __restrict__ cb, const float* __restrict__ locw,
    const float* __restrict__ locb, const float* __restrict__ scow,
    const float* __restrict__ scob, float* __restrict__ out) {
  const int tb_ = blockIdx.x;
  const int b = blockIdx.y;
  int H, locbase, ncol, tile;
  const float* fmb;
  if (tb_ < 325)      { H = 200; locbase = 0;     ncol = 25; tile = tb_;       fmb = fm0; }
  else if (tb_ < 416) { H = 100; locbase = 40000; ncol = 13; tile = tb_ - 325; fmb = fm1; }
  else if (tb_ < 444) { H = 50;  locbase = 50000; ncol = 7;  tile = tb_ - 416; fmb = fm2; }
  else                { H = 25;  locbase = 52500; ncol = 4;  tile = tb_ - 444; fmb = fm3; }
  const int W = H;
  const int ty_t = tile / ncol, tx_t = tile - ty_t * ncol;
  const int y0 = ty_t * 16, x0 = tx_t * 8;
  fmb += (size_t)b * 512 * H * W;

  const int tid = threadIdx.x;
  const int pxg = tid & 15;        // tile row 0..15
  const int ocg = tid >> 4;        // 0..31, 16 oc each

  __shared__ alignas(16) union LDS {
    struct { float w[9216]; float in[2][18][12]; } m;   // 38592 B
    struct { float h[128 * 132]; float w1[2304]; } e;   // 76800 B
  } lds;

  float acc[8][16];
#pragma unroll
  for (int q = 0; q < 8; q++)
#pragma unroll
    for (int i = 0; i < 16; i++) acc[q][i] = 0.f;

  // input-halo staging geometry: 2 ic planes x 18 rows x 10 cols = 360
  const bool stg = (tid < 360);
  int sic = 0, srr = 0, scc = 0; bool sok = false; size_t soff = 0;
  if (stg) {
    sic = tid / 180; int rem = tid % 180; srr = rem / 10; scc = rem % 10;
    int yy = y0 - 1 + srr, xx = x0 - 1 + scc;
    sok = (yy >= 0 && yy < H && xx >= 0 && xx < W);
    if (sok) soff = ((size_t)sic * H + yy) * W + xx;
  }
  const size_t icstep = (size_t)2 * H * W;

#pragma unroll 1
  for (int t = 0; t < 256; ++t) {
    __syncthreads();                       // protect LDS from prev-iter reads
    const float2* wsrc = reinterpret_cast<const float2*>(wT + (size_t)t * 9216);
    float2* wdst = reinterpret_cast<float2*>(lds.m.w);
#pragma unroll
    for (int r = 0; r < 9; r++) wdst[r * 512 + tid] = wsrc[r * 512 + tid];
    if (stg) {
      float v = 0.f;
      if (sok) v = fmb[(size_t)t * icstep + soff];
      lds.m.in[sic][srr][scc] = v;
    }
    __syncthreads();
#pragma unroll
    for (int ic = 0; ic < 2; ic++) {
#pragma unroll
      for (int ky = 0; ky < 3; ky++) {
        const float* rowp = &lds.m.in[ic][pxg + ky][0];   // cols -1..8 -> 10 floats
        float4 ra = *reinterpret_cast<const float4*>(rowp);
        float4 rb = *reinterpret_cast<const float4*>(rowp + 4);
        float2 rc = *reinterpret_cast<const float2*>(rowp + 8);
        float r[10] = {ra.x, ra.y, ra.z, ra.w, rb.x, rb.y, rb.z, rb.w, rc.x, rc.y};
#pragma unroll
        for (int kx = 0; kx < 3; kx++) {
          const float4* wp = reinterpret_cast<const float4*>(
              &lds.m.w[(ic * 9 + ky * 3 + kx) * 512 + ocg * 16]);
#pragma unroll
          for (int v4 = 0; v4 < 4; v4++) {
            float4 wv = wp[v4];
#pragma unroll
            for (int q = 0; q < 8; q++) {
              float iv = r[q + kx];
              acc[q][v4 * 4 + 0] = fmaf(iv, wv.x, acc[q][v4 * 4 + 0]);
              acc[q][v4 * 4 + 1] = fmaf(iv, wv.y, acc[q][v4 * 4 + 1]);
              acc[q][v4 * 4 + 2] = fmaf(iv, wv.z, acc[q][v4 * 4 + 2]);
              acc[q][v4 * 4 + 3] = fmaf(iv, wv.w, acc[q][v4 * 4 + 3]);
            }
          }
        }
      }
    }
  }
  // bias + relu
#pragma unroll
  for (int i = 0; i < 16; i++) {
    float bb = cb[ocg * 16 + i];
#pragma unroll
    for (int q = 0; q < 8; q++) acc[q][i] = fmaxf(__fadd_rn(acc[q][i], bb), 0.f);
  }

  // fused 1x1 heads: 18 ch (12 loc + 6 score) x 128 px, 4 oc-chunks of 128.
  // h layout [px][132]; reads use per-lane slot rotation: bank-quad =
  // (2*px + j) % 32 -> 2-way (free) instead of R2's 8-way (1.77e8 confl).
  float part[5] = {0.f, 0.f, 0.f, 0.f, 0.f};
#pragma unroll 1
  for (int c = 0; c < 4; c++) {
    __syncthreads();
    for (int idx = tid; idx < 2304; idx += 512) {
      int ch = idx >> 7, j = idx & 127;
      lds.e.w1[idx] = (ch < 12) ? locw[ch * 512 + c * 128 + j]
                                : scow[(ch - 12) * 512 + c * 128 + j];
    }
    if ((ocg >> 3) == c) {
      int ocl = (ocg & 7) * 16;
#pragma unroll
      for (int q = 0; q < 8; q++)
#pragma unroll
        for (int i4 = 0; i4 < 4; i4++)
          *reinterpret_cast<float4*>(&lds.e.h[(pxg * 8 + q) * 132 + ocl + i4 * 4]) =
              *reinterpret_cast<const float4*>(&acc[q][i4 * 4]);
    }
    __syncthreads();
#pragma unroll 1
    for (int pp = 0; pp < 5; pp++) {
      int pair = tid + pp * 512;
      if (pair < 2304) {
        int px = pair & 127, ch = pair >> 7;
        const float* hb = &lds.e.h[px * 132];
        const float* w1b = &lds.e.w1[ch * 128];
        float s = part[pp];
#pragma unroll
        for (int j = 0; j < 32; j++) {
          int slot = (j + px) & 31;
          float4 h4 = *reinterpret_cast<const float4*>(hb + slot * 4);
          float4 w4 = *reinterpret_cast<const float4*>(w1b + slot * 4);
          s = fmaf(h4.x, w4.x, fmaf(h4.y, w4.y, fmaf(h4.z, w4.z, fmaf(h4.w, w4.w, s))));
        }
        part[pp] = s;
      }
    }
  }
  // write NHWC-flattened loc/score outputs
#pragma unroll 1
  for (int pp = 0; pp < 5; pp++) {
    int pair = tid + pp * 512;
    if (pair < 2304) {
      int px = pair & 127, ch = pair >> 7;
      int y = y0 + (px >> 3), x = x0 + (px & 7);
      if (y < H && x < W) {
        int k = locbase + y * W + x;
        if (ch < 12) {
          int a = ch >> 2, d = ch & 3;
          int n = 3 * k + a;
          out[OFF_LOCS + ((size_t)b * NA + n) * 4 + d] = __fadd_rn(part[pp], locb[ch]);
        } else {
          int s = ch - 12, a = s >> 1, si = s & 1;
          int n = 3 * k + a;
          out[OFF_SCORES + ((size_t)b * NA + n) * 2 + si] = __fadd_rn(part[pp], scob[s]);
        }
      }
    }
  }
}

// ---------------- anchors (double math to mirror numpy exactly)
__global__ void k_anchors(float* __restrict__ out) {
  int n = blockIdx.x * 256 + threadIdx.x;
  if (n >= NA) return;
  int a = n % 3, k = n / 3;
  int base, Wl, stride, scale;
  if (k < 40000)      { base = 0;     Wl = 200; stride = 4;  scale = 4; }
  else if (k < 50000) { base = 40000; Wl = 100; stride = 8;  scale = 8; }
  else if (k < 52500) { base = 50000; Wl = 50;  stride = 16; scale = 16; }
  else                { base = 52500; Wl = 25;  stride = 32; scale = 32; }
  int kk = k - base;
  int ky = kk / Wl, kx = kk - ky * Wl;
  double r = (a == 0) ? 0.5 : ((a == 1) ? 1.0 : 2.0);
  double sc = (double)scale;
  double h = (16.0 * sc) * sqrt(r);
  double w = (16.0 * sc) * sqrt(1.0 / r);
  float ab0 = (float)(8.0 - h / 2.0), ab1 = (float)(8.0 - w / 2.0);
  float ab2 = (float)(8.0 + h / 2.0), ab3 = (float)(8.0 + w / 2.0);
  double sy = (double)(ky * stride), sx = (double)(kx * stride);
  out[OFF_ANCH + (size_t)n * 4 + 0] = (float)((double)ab0 + sy);
  out[OFF_ANCH + (size_t)n * 4 + 1] = (float)((double)ab1 + sx);
  out[OFF_ANCH + (size_t)n * 4 + 2] = (float)((double)ab2 + sy);
  out[OFF_ANCH + (size_t)n * 4 + 3] = (float)((double)ab3 + sx);
}

// ---------------- zero hists + counters
__global__ void k_zero(unsigned* hhi, unsigned* hlo, unsigned* misc) {
  int i = blockIdx.x * 256 + threadIdx.x;
  if (i < 2 * 65536) { hhi[i] = 0u; hlo[i] = 0u; }
  if (i < 64) misc[i] = 0u;
}

// ---------------- decode boxes, fg softmax, validity mask, monotone key
__global__ void k_decode(const float* __restrict__ out, float* __restrict__ boxes,
                         unsigned* __restrict__ keys, const int* __restrict__ ihp,
                         const int* __restrict__ iwp) {
  int n = blockIdx.x * 256 + threadIdx.x;
  int b = blockIdx.y;
  if (n >= NA) return;
  const float* an = out + OFF_ANCH + (size_t)n * 4;
  float a0 = an[0], a1 = an[1], a2 = an[2], a3 = an[3];
  const float* lc = out + OFF_LOCS + ((size_t)b * NA + n) * 4;
  float l0 = lc[0], l1 = lc[1], l2 = lc[2], l3 = lc[3];
  const float* sp = out + OFF_SCORES + ((size_t)b * NA + n) * 2;
  float s0 = sp[0], s1 = sp[1];
  float m = fmaxf(s0, s1);
  float e0 = expf(__fsub_rn(s0, m)), e1 = expf(__fsub_rn(s1, m));
  float fg = __fdiv_rn(e1, __fadd_rn(e0, e1));
  float ah = __fsub_rn(a2, a0), aw = __fsub_rn(a3, a1);
  float acy = __fadd_rn(a0, __fmul_rn(0.5f, ah));
  float acx = __fadd_rn(a1, __fmul_rn(0.5f, aw));
  float cy = __fadd_rn(__fmul_rn(l0, ah), acy);
  float cx = __fadd_rn(__fmul_rn(l1, aw), acx);
  float hh = __fmul_rn(expf(l2), ah), ww = __fmul_rn(expf(l3), aw);
  float y1 = __fsub_rn(cy, __fmul_rn(0.5f, hh));
  float x1 = __fsub_rn(cx, __fmul_rn(0.5f, ww));
  float y2 = __fadd_rn(cy, __fmul_rn(0.5f, hh));
  float x2 = __fadd_rn(cx, __fmul_rn(0.5f, ww));
  float fh = (float)ihp[0], fw = (float)iwp[0];
  y1 = fminf(fmaxf(y1, 0.f), fh); x1 = fminf(fmaxf(x1, 0.f), fw);
  y2 = fminf(fmaxf(y2, 0.f), fh); x2 = fminf(fmaxf(x2, 0.f), fw);
  float hs = __fsub_rn(y2, y1), wsz = __fsub_rn(x2, x1);
  bool valid = (hs >= 16.f) && (wsz >= 16.f);
  float scv = valid ? fg : -INFINITY;
  size_t bi = (size_t)b * NA + n;
  boxes[bi * 4 + 0] = y1; boxes[bi * 4 + 1] = x1;
  boxes[bi * 4 + 2] = y2; boxes[bi * 4 + 3] = x2;
  unsigned u = __float_as_uint(scv);
  keys[bi] = (u & 0x80000000u) ? ~u : (u | 0x80000000u);
}

__global__ void k_hist_hi(const unsigned* __restrict__ keys, unsigned* __restrict__ hhi) {
  int n = blockIdx.x * 256 + threadIdx.x;
  int b = blockIdx.y;
  if (n >= NA) return;
  unsigned k = keys[(size_t)b * NA + n];
  atomicAdd(&hhi[b * 65536 + (k >> 16)], 1u);
}

__global__ void k_hist_lo(const unsigned* __restrict__ keys, const unsigned* __restrict__ misc,
                          unsigned* __restrict__ hlo) {
  int n = blockIdx.x * 256 + threadIdx.x;
  int b = blockIdx.y;
  if (n >= NA) return;
  unsigned bhi = misc[b * 32 + 2];
  unsigned k = keys[(size_t)b * NA + n];
  if ((k >> 16) == bhi) atomicAdd(&hlo[b * 65536 + (k & 0xFFFFu)], 1u);
}

// find the target-th largest bucket; mode0: target=2000 over hi16, mode1: rank over lo16
__global__ __launch_bounds__(1024) void k_scan(const unsigned* __restrict__ hist,
                                               unsigned* __restrict__ misc, int mode) {
  int b = blockIdx.x;
  const unsigned* h = hist + (size_t)b * 65536;
  unsigned* mc = misc + b * 32;
  __shared__ unsigned part[1024];
  int t = threadIdx.x;
  unsigned target = (mode == 0) ? 2000u : mc[3];
  unsigned s = 0;
  for (int i = 0; i < 64; i++) s += h[t * 64 + i];
  part[t] = s;
  __syncthreads();
  if (t == 0) {
    unsigned cum = 0; int seg = 0;
    for (int u = 1023; u >= 0; --u) {
      if (cum + part[u] >= target) { seg = u; break; }
      cum += part[u];
    }
    unsigned c2 = cum; int bin = seg * 64;
    for (int v = seg * 64 + 63; v >= seg * 64; --v) {
      if (c2 + h[v] >= target) { bin = v; break; }
      c2 += h[v];
    }
    if (mode == 0) { mc[2] = (unsigned)bin; mc[3] = target - c2; }
    else {
      unsigned T = (mc[2] << 16) | (unsigned)bin;
      unsigned cnt_gt = (2000u - mc[3]) + c2;
      mc[4] = T; mc[5] = cnt_gt; mc[6] = 2000u - cnt_gt;
    }
  }
}

__global__ void k_collect(const unsigned* __restrict__ keys, unsigned* __restrict__ misc,
                          unsigned long long* __restrict__ sel, unsigned* __restrict__ ties) {
  int n = blockIdx.x * 256 + threadIdx.x;
  int b = blockIdx.y;
  if (n >= NA) return;
  unsigned T = misc[b * 32 + 4];
  unsigned k = keys[(size_t)b * NA + n];
  if (k > T) {
    unsigned p = atomicAdd(&misc[b * 32 + 0], 1u);
    if (p < 2048) sel[(size_t)b * 2048 + p] = ((unsigned long long)k << 32) | (unsigned)(~n);
  } else if (k == T) {
    unsigned p = atomicAdd(&misc[b * 32 + 1], 1u);
    if (p < 8192) ties[(size_t)b * 8192 + p] = (unsigned)n;
  }
}

// build top-2000 sorted by (score desc, idx asc); gather boxes; init keep bits
__global__ __launch_bounds__(1024) void k_final(
    const unsigned long long* __restrict__ sel, const unsigned* __restrict__ ties,
    const unsigned* __restrict__ misc, const float* __restrict__ boxes,
    float* __restrict__ tb, unsigned long long* __restrict__ keepw) {
  int b = blockIdx.x, t = threadIdx.x;
  __shared__ unsigned tie_s[8192];
  __shared__ unsigned long long arr[2048];
  __shared__ unsigned long long kw[32];
  unsigned cnt_gt = misc[b * 32 + 5];
  unsigned cnt_eq = misc[b * 32 + 1]; if (cnt_eq > 8192u) cnt_eq = 8192u;
  unsigned T = misc[b * 32 + 4];
  unsigned msort = 64;
  while (msort < cnt_eq) msort <<= 1;
  for (int i = t; i < 8192; i += 1024)
    tie_s[i] = (i < (int)cnt_eq) ? ties[(size_t)b * 8192 + i] : 0xFFFFFFFFu;
  __syncthreads();
  for (unsigned kk = 2; kk <= msort; kk <<= 1)
    for (unsigned j = kk >> 1; j > 0; j >>= 1) {
      for (int i = t; i < (int)msort; i += 1024) {
        int l = i ^ (int)j;
        if (l > i) {
          unsigned a = tie_s[i], c = tie_s[l];
          bool up = ((i & kk) == 0);               // ascending
          if ((a > c) == up) { tie_s[i] = c; tie_s[l] = a; }
        }
      }
      __syncthreads();
    }
  for (int i = t; i < 2048; i += 1024) {
    unsigned long long v = 0ull;
    if (i < (int)cnt_gt) v = sel[(size_t)b * 2048 + i];
    else if (i < 2000) {
      unsigned n = tie_s[i - cnt_gt];
      v = ((unsigned long long)T << 32) | (unsigned)(~n);
    }
    arr[i] = v;
  }
  __syncthreads();
  for (unsigned kk = 2; kk <= 2048; kk <<= 1)
    for (unsigned j = kk >> 1; j > 0; j >>= 1) {
      for (int i = t; i < 2048; i += 1024) {
        int l = i ^ (int)j;
        if (l > i) {
          unsigned long long a = arr[i], c = arr[l];
          bool dir = ((i & kk) != 0);              // descending overall
          if ((a > c) == dir) { arr[i] = c; arr[l] = a; }
        }
      }
      __syncthreads();
    }
  if (t < 32) kw[t] = 0ull;
  __syncthreads();
  for (int j = t; j < 2000; j += 1024) {
    unsigned long long v = arr[j];
    unsigned n = ~(unsigned)(v & 0xFFFFFFFFull);
    unsigned key = (unsigned)(v >> 32);
    const float* bp = boxes + ((size_t)b * NA + n) * 4;
    float* tp = tb + ((size_t)b * 2000 + j) * 4;
    tp[0] = bp[0]; tp[1] = bp[1]; tp[2] = bp[2]; tp[3] = bp[3];
    if (key > MONO_NEGINF) atomicOr(&kw[j >> 6], 1ull << (j & 63));
  }
  __syncthreads();
  if (t < 32) keepw[b * 32 + t] = kw[t];
}

// ---------------- IoU suppression bitmask (j > i, iou > 0.7)
__device__ __forceinline__ int swz(int i) { return i + (i >> 8); }
__global__ __launch_bounds__(256) void k_iou(const float* __restrict__ tb,
                                             unsigned long long* __restrict__ mask) {
  int b = blockIdx.y;
  __shared__ float bx[8032];
  const float* tbb = tb + (size_t)b * 2000 * 4;
  for (int i = threadIdx.x; i < 8000; i += 256) bx[swz(i)] = tbb[i];
  __syncthreads();
  int il = threadIdx.x >> 5, w = threadIdx.x & 31;
  int i = blockIdx.x * 8 + il;
  int ib = i * 4, ip = ib + (ib >> 8);
  float y1 = bx[ip], x1 = bx[ip + 1], y2 = bx[ip + 2], x2 = bx[ip + 3];
  float ai = __fmul_rn(__fsub_rn(y2, y1), __fsub_rn(x2, x1));
  unsigned long long m = 0ull;
  int j0 = w * 64;
  for (int l = 0; l < 64; l++) {
    int j = j0 + l;
    if (j < 2000 && j > i) {
      int jb = j * 4, jp = jb + (jb >> 8);
      float yy1 = bx[jp], xx1 = bx[jp + 1], yy2 = bx[jp + 2], xx2 = bx[jp + 3];
      float aj = __fmul_rn(__fsub_rn(yy2, yy1), __fsub_rn(xx2, xx1));
      float iy = fmaxf(0.f, __fsub_rn(fminf(y2, yy2), fmaxf(y1, yy1)));
      float ix = fmaxf(0.f, __fsub_rn(fminf(x2, xx2), fmaxf(x1, xx1)));
      float inter = __fmul_rn(iy, ix);
      float den = __fadd_rn(__fsub_rn(__fadd_rn(ai, aj), inter), 1e-10f);
      if (__fdiv_rn(inter, den) > 0.7f) m |= (1ull << l);
    }
  }
  mask[((size_t)b * 2000 + i) * 32 + w] = m;
}

// ---------------- sequential greedy NMS (1 wave per image)
__device__ __forceinline__ unsigned long long shfl64(unsigned long long v, int src) {
  int lo = __shfl((int)(v & 0xFFFFFFFFull), src, 64);
  int hi = __shfl((int)(v >> 32), src, 64);
  return ((unsigned long long)(unsigned)hi << 32) | (unsigned)lo;
}
__global__ __launch_bounds__(64) void k_nms(const unsigned long long* __restrict__ mask,
                                            unsigned long long* __restrict__ keepw) {
  int b = blockIdx.x, lane = threadIdx.x;
  __shared__ unsigned long long rows[64][33];
  unsigned long long k = (lane < 32) ? keepw[b * 32 + lane] : 0ull;
  const unsigned long long* mb = mask + (size_t)b * 2000 * 32;
  for (int c = 0; c < 32; c++) {
    __syncthreads();
    for (int it = 0; it < 32; it++) {
      int idx = it * 64 + lane;
      int r = idx >> 5, w = idx & 31;
      int gi = c * 64 + r;
      rows[r][w] = (gi < 2000) ? mb[(size_t)gi * 32 + w] : 0ull;
    }
    __syncthreads();
    for (int il = 0; il < 64; il++) {
      int i = c * 64 + il;
      if (i >= 2000) break;
      unsigned long long kv = shfl64(k, i >> 6);
      if ((kv >> (i & 63)) & 1ull) {
        if (lane < 32) k &= ~rows[il][lane];
      }
    }
  }
  if (lane < 32) keepw[b * 32 + lane] = k;
}

// ---------------- compact kept boxes -> rois (+zero pad) + roi_indices
__global__ __launch_bounds__(1024) void k_rois(const unsigned long long* __restrict__ keepw,
                                               const float* __restrict__ tb,
                                               float* __restrict__ out) {
  int b = blockIdx.x, t = threadIdx.x;
  __shared__ unsigned long long kws[32];
  __shared__ unsigned pre[33];
  if (t < 32) kws[t] = keepw[b * 32 + t];
  __syncthreads();
  if (t == 0) {
    unsigned c = 0;
    for (int w = 0; w < 32; w++) { pre[w] = c; c += __popcll(kws[w]); }
    pre[32] = c;
  }
  __syncthreads();
  unsigned total = pre[32];
  for (int j = t; j < 2000; j += 1024) {
    unsigned long long kv = kws[j >> 6];
    if ((kv >> (j & 63)) & 1ull) {
      unsigned rank = pre[j >> 6] + (unsigned)__popcll(kv & ((1ull << (j & 63)) - 1ull));
      if (rank < 300) {
        const float* tp = tb + ((size_t)b * 2000 + j) * 4;
        float* op = out + OFF_ROIS + ((size_t)b * 300 + rank) * 4;
        op[0] = tp[0]; op[1] = tp[1]; op[2] = tp[2]; op[3] = tp[3];
      }
    }
  }
  for (int r = t; r < 300; r += 1024) {
    if ((unsigned)r >= total) {
      float* op = out + OFF_ROIS + ((size_t)b * 300 + r) * 4;
      op[0] = 0.f; op[1] = 0.f; op[2] = 0.f; op[3] = 0.f;
    }
    out[OFF_RI + b * 300 + r] = (float)b;
  }
}

extern "C" void kernel_launch(void* const* d_in, const int* in_sizes, int n_in,
                              void* d_out, int out_size, void* d_ws, size_t ws_size,
                              hipStream_t stream) {
  const float* fm0 = (const float*)d_in[0];
  const float* fm1 = (const float*)d_in[1];
  const float* fm2 = (const float*)d_in[2];
  const float* fm3 = (const float*)d_in[3];
  const float* cw  = (const float*)d_in[4];
  const float* cb  = (const float*)d_in[5];
  const float* scw = (const float*)d_in[6];
  const float* scb = (const float*)d_in[7];
  const float* lw  = (const float*)d_in[8];
  const float* lb  = (const float*)d_in[9];
  const int* ih = (const int*)d_in[10];
  const int* iw = (const int*)d_in[11];
  float* out = (float*)d_out;
  char* wsb = (char*)d_ws;

  auto al = [](size_t x) { return (x + 511) & ~(size_t)511; };
  size_t off = 0;
  float* wT = (float*)(wsb + off);                 off = al(off + (size_t)512 * 512 * 9 * 4);
  float* boxes = (float*)(wsb + off);              off = al(off + (size_t)2 * NA * 4 * 4);
  unsigned* keys = (unsigned*)(wsb + off);         off = al(off + (size_t)2 * NA * 4);
  unsigned* hhi = (unsigned*)(wsb + off);          off = al(off + (size_t)2 * 65536 * 4);
  unsigned* hlo = (unsigned*)(wsb + off);          off = al(off + (size_t)2 * 65536 * 4);
  unsigned* misc = (unsigned*)(wsb + off);         off = al(off + 64 * 4);
  unsigned long long* sel = (unsigned long long*)(wsb + off);  off = al(off + (size_t)2 * 2048 * 8);
  unsigned* ties = (unsigned*)(wsb + off);         off = al(off + (size_t)2 * 8192 * 4);
  float* tb = (float*)(wsb + off);                 off = al(off + (size_t)2 * 2000 * 4 * 4);
  unsigned long long* mask = (unsigned long long*)(wsb + off); off = al(off + (size_t)2 * 2000 * 32 * 8);
  unsigned long long* keep = (unsigned long long*)(wsb + off); off = al(off + (size_t)2 * 32 * 8);
  (void)ws_size; (void)in_sizes; (void)n_in; (void)out_size;

  k_wT<<<dim3((512 * 512 * 9 + 255) / 256), dim3(256), 0, stream>>>(cw, wT);

  // tiles: L0 13x25=325, L1 7x13=91, L2 4x7=28, L3 2x4=8 -> 452 x 2 images
  k_conv<<<dim3(452, 2), dim3(512), 0, stream>>>(fm0, fm1, fm2, fm3, wT, cb,
                                                 lw, lb, scw, scb, out);
  k_anchors<<<dim3(623), dim3(256), 0, stream>>>(out);
  k_zero<<<dim3(512), dim3(256), 0, stream>>>(hhi, hlo, misc);
  k_decode<<<dim3(623, 2), dim3(256), 0, stream>>>(out, boxes, keys, ih, iw);
  k_hist_hi<<<dim3(623, 2), dim3(256), 0, stream>>>(keys, hhi);
  k_scan<<<dim3(2), dim3(1024), 0, stream>>>(hhi, misc, 0);
  k_hist_lo<<<dim3(623, 2), dim3(256), 0, stream>>>(keys, misc, hlo);
  k_scan<<<dim3(2), dim3(1024), 0, stream>>>(hlo, misc, 1);
  k_collect<<<dim3(623, 2), dim3(256), 0, stream>>>(keys, misc, sel, ties);
  k_final<<<dim3(2), dim3(1024), 0, stream>>>(sel, ties, misc, boxes, tb, keep);
  k_iou<<<dim3(250, 2), dim3(256), 0, stream>>>(tb, mask);
  k_nms<<<dim3(2), dim3(64), 0, stream>>>(mask, keep);
  k_rois<<<dim3(2), dim3(1024), 0, stream>>>(keep, tb, out);
}